// Round 17
// baseline (957.004 us; speedup 1.0000x reference)
//
#include <hip/hip_runtime.h>
#include <cstdint>
#include <cstddef>

// ---------------------------------------------------------------------------
// VQ-VAE forward. B=16384 F=4096 H=512 D=64 K=512
// enc1/dec3 use SWAPPED-OPERAND MFMA (mfma(B,A)): output fragment holds 4
// consecutive COLS per reg -> float4 stores (4x fewer store instructions).
// Values bit-identical (mul commutes; MFMA K-tree fixed by k index).
// Everything else identical to the 950us r16 kernel.
// ---------------------------------------------------------------------------

static constexpr int BB = 16384;

typedef __attribute__((ext_vector_type(8))) short short8;
typedef __attribute__((ext_vector_type(8))) _Float16 half8;
typedef __attribute__((ext_vector_type(4))) float f32x4;

__device__ __forceinline__ unsigned short f2bf(float f) {
    union { float f; uint32_t u; } v; v.f = f;
    uint32_t r = (v.u + 0x7FFFu + ((v.u >> 16) & 1u)) >> 16;
    return (unsigned short)r;
}

// producer-fenced raw barrier: my LDS ops done -> barrier. vmcnt NOT drained,
// so global prefetches survive the barrier (unlike __syncthreads).
__device__ __forceinline__ void lds_barrier() {
    asm volatile("s_waitcnt lgkmcnt(0)" ::: "memory");
    __builtin_amdgcn_s_barrier();
    __builtin_amdgcn_sched_barrier(0);
}

// WT[c][r] = bf16(W[r][c]); W is R x Cc
__global__ __launch_bounds__(256) void transpose_cast(
    const float* __restrict__ W, unsigned short* __restrict__ WT, int R, int Cc)
{
    __shared__ float s[32][33];
    const int tx = threadIdx.x & 31, ty = threadIdx.x >> 5;
    const int c0 = blockIdx.x * 32, r0 = blockIdx.y * 32;
#pragma unroll
    for (int i = 0; i < 4; i++)
        s[ty + i * 8][tx] = W[(size_t)(r0 + ty + i * 8) * Cc + c0 + tx];
    __syncthreads();
#pragma unroll
    for (int i = 0; i < 4; i++)
        WT[(size_t)(c0 + ty + i * 8) * R + r0 + tx] = f2bf(s[tx][ty + i * 8]);
}

// per-block body of the fp16 hi/lo transpose-split (bx,by = tile coords)
__device__ __forceinline__ void tsplit_blk(
    const float* __restrict__ W, unsigned short* __restrict__ Th,
    unsigned short* __restrict__ Tl, int R, int Cc, int bx, int by,
    float (&s)[32][33])
{
    const int tx = threadIdx.x & 31, ty = threadIdx.x >> 5;
    const int c0 = bx * 32, r0 = by * 32;
#pragma unroll
    for (int i = 0; i < 4; i++)
        s[ty + i * 8][tx] = W[(size_t)(r0 + ty + i * 8) * Cc + c0 + tx];
    __syncthreads();
#pragma unroll
    for (int i = 0; i < 4; i++) {
        const float f = s[tx][ty + i * 8];
        const _Float16 h = (_Float16)f;
        const float fh = (float)h;
        const _Float16 lo = (_Float16)((f - fh) * 4096.0f);
        union { _Float16 hf; unsigned short u; } ch, cl;
        ch.hf = h; cl.hf = lo;
        Th[(size_t)(c0 + ty + i * 8) * R + r0 + tx] = ch.u;
        Tl[(size_t)(c0 + ty + i * 8) * R + r0 + tx] = cl.u;
    }
}

// ALL weight prep in one launch. Segments (block ranges):
//   [0,1024)   We1 (8x128)   [1024,1056) We2 (4x8)   [1056,1120) We3 (16x4)
//   [1120,1184) Wd1 (4x16)   [1184,1216) Wd2 (8x4)   [1216,1248) cb  (16x2)
//   [1248,1250) w2g (2 x 256 threads)
__global__ __launch_bounds__(256) void prep_all(
    const float* __restrict__ We1, unsigned short* __restrict__ B1h, unsigned short* __restrict__ B1l,
    const float* __restrict__ We2, unsigned short* __restrict__ W2h, unsigned short* __restrict__ W2l,
    const float* __restrict__ We3, unsigned short* __restrict__ W3h, unsigned short* __restrict__ W3l,
    const float* __restrict__ Wd1, unsigned short* __restrict__ Wd1h, unsigned short* __restrict__ Wd1l,
    const float* __restrict__ Wd2, unsigned short* __restrict__ Wd2h, unsigned short* __restrict__ Wd2l,
    const float* __restrict__ cb,  unsigned short* __restrict__ cbTh, unsigned short* __restrict__ cbTl,
    float* __restrict__ w2g)
{
    __shared__ float s[32][33];
    const int b = blockIdx.x;
    if (b < 1024) {
        tsplit_blk(We1, B1h, B1l, 4096, 256, b & 7, b >> 3, s);
    } else if (b < 1056) {
        const int bb = b - 1024; tsplit_blk(We2, W2h, W2l, 256, 128, bb & 3, bb >> 2, s);
    } else if (b < 1120) {
        const int bb = b - 1056; tsplit_blk(We3, W3h, W3l, 128, 512, bb & 15, bb >> 4, s);
    } else if (b < 1184) {
        const int bb = b - 1120; tsplit_blk(Wd1, Wd1h, Wd1l, 512, 128, bb & 3, bb >> 2, s);
    } else if (b < 1216) {
        const int bb = b - 1184; tsplit_blk(Wd2, Wd2h, Wd2l, 128, 256, bb & 7, bb >> 3, s);
    } else if (b < 1248) {
        const int bb = b - 1216; tsplit_blk(cb, cbTh, cbTl, 64, 512, bb & 15, bb >> 4, s);
    } else {
        const int k = (b - 1248) * 256 + threadIdx.x;
        float sm = 0.f;
        for (int d = 0; d < 64; d++) { float c = cb[d * 512 + k]; sm = fmaf(c, c, sm); }
        w2g[k] = sm;
    }
}

// ---------------- enc1: fp16x2-split MFMA, raw-barrier pipelined ------------
// Split-K=4 (KS=1024 per block). A-queue depth 2. SWAPPED MFMA operands:
// output fragment = 4 consecutive cols per reg -> float4 partial stores.
static constexpr int E1KS = 1024;

template<int BUF>
__device__ __forceinline__ void enc1_step(
    int K0,
    const float* __restrict__ gA,
    const unsigned short* __restrict__ gBh,
    const unsigned short* __restrict__ gBl,
    short (&Ah)[2][2048], short (&Al)[2][2048],
    half8 (&bhC)[4], half8 (&bhN)[4], half8 (&blS)[4],
    f32x4& p0, f32x4& p1, f32x4& q0, f32x4& q1,
    f32x4 (&acc1)[4][4], f32x4 (&acc2)[4][4],
    int aoff, int fr0)
{
    constexpr size_t rstep = (size_t)16 * 4096;   // next t-block (16 rows)
    const int kn1 = K0 + 32, kn3 = K0 + 96;
    lds_barrier();   // LDS[BUF] visible; global prefetches stay in flight
#pragma unroll
    for (int j = 0; j < 4; j++)
        blS[j] = *(const half8*)(gBl + (size_t)j * rstep + K0);
    if (kn1 < E1KS) {
#pragma unroll
        for (int j = 0; j < 4; j++)
            bhN[j] = *(const half8*)(gBh + (size_t)j * rstep + kn1);
    }
    f32x4 f0, f1;
    if (kn3 < E1KS) {
        f0 = __builtin_nontemporal_load((const f32x4*)(gA + kn3));
        f1 = __builtin_nontemporal_load((const f32x4*)(gA + kn3 + 4));
    }
    half8 ah[4];
#pragma unroll
    for (int i = 0; i < 4; i++)
        ah[i] = *(const half8*)&Ah[BUF][(i << 9) + fr0];
#pragma unroll
    for (int i = 0; i < 4; i++)
#pragma unroll
        for (int j = 0; j < 4; j++)
            acc1[i][j] = __builtin_amdgcn_mfma_f32_16x16x32_f16(
                bhC[j], ah[i], acc1[i][j], 0, 0, 0);
#pragma unroll
    for (int i = 0; i < 4; i++)
#pragma unroll
        for (int j = 0; j < 4; j++)
            acc2[i][j] = __builtin_amdgcn_mfma_f32_16x16x32_f16(
                blS[j], ah[i], acc2[i][j], 0, 0, 0);
    half8 al[4];
#pragma unroll
    for (int i = 0; i < 4; i++)
        al[i] = *(const half8*)&Al[BUF][(i << 9) + fr0];
#pragma unroll
    for (int i = 0; i < 4; i++)
#pragma unroll
        for (int j = 0; j < 4; j++)
            acc2[i][j] = __builtin_amdgcn_mfma_f32_16x16x32_f16(
                bhC[j], al[i], acc2[i][j], 0, 0, 0);
    if (kn1 < E1KS) {
        // convert A(K0+32): loaded 2 steps ago -> wait fully hidden
        float fv[8];
        *(f32x4*)&fv[0] = p0;
        *(f32x4*)&fv[4] = p1;
        union { _Float16 h[8]; short8 s; } uh, ul;
#pragma unroll
        for (int e = 0; e < 8; e++) {
            const float f = fv[e];
            const _Float16 h = (_Float16)f;
            const float fh = (float)h;
            uh.h[e] = h;
            ul.h[e] = (_Float16)((f - fh) * 4096.0f);
        }
        *(short8*)&Ah[BUF ^ 1][aoff] = uh.s;
        *(short8*)&Al[BUF ^ 1][aoff] = ul.s;
    }
    p0 = q0; p1 = q1;
    if (kn3 < E1KS) { q0 = f0; q1 = f1; }
}

__global__ __launch_bounds__(256, 2) void gemm_f16x2_enc1(
    const float* __restrict__ X,             // 16384 x 4096 f32
    const unsigned short* __restrict__ Bh,   // 256 x 4096 f16 (We1^T hi)
    const unsigned short* __restrict__ Bl,   // 256 x 4096 f16 (We1^T lo*2^12)
    float* __restrict__ part)                // [4][16384][256] f32
{
    __shared__ short Ah[2][2048];    // 4 t-blocks (64 rows) frag-order, 8 KB
    __shared__ short Al[2][2048];
    const int tid = threadIdx.x;
    const int l = tid & 63, w = tid >> 6;     // 4 waves; wave w -> cols w*64
    const int lm = l & 15, lq = l >> 4;
    const int bm = blockIdx.y * 64;
    const int kStart = blockIdx.z * E1KS;

    const float* gA = X + (size_t)(bm + w * 16 + lm) * 4096 + kStart + lq * 8;
    const unsigned short* gBh = Bh + (size_t)(w * 64 + lm) * 4096 + kStart + lq * 8;
    const unsigned short* gBl = Bl + (size_t)(w * 64 + lm) * 4096 + kStart + lq * 8;
    constexpr size_t rstep = (size_t)16 * 4096;

    const int aoff = (w << 9) + (l << 3);     // A store slot (shorts)
    const int fr0 = (lq << 7) + (lm << 3);    // frag lane offset

    f32x4 acc1[4][4], acc2[4][4];
#pragma unroll
    for (int i = 0; i < 4; i++)
#pragma unroll
        for (int j = 0; j < 4; j++) {
            acc1[i][j] = (f32x4){0.f, 0.f, 0.f, 0.f};
            acc2[i][j] = (f32x4){0.f, 0.f, 0.f, 0.f};
        }

    half8 bhA[4], bhB[4], blS[4];
    f32x4 p0, p1, q0, q1;

    // prologue: B(0) hi -> bhA; A(0) -> convert -> LDS[0];
    // A(32) -> p regs; A(64) -> q regs (queue depth 2)
    {
#pragma unroll
        for (int j = 0; j < 4; j++)
            bhA[j] = *(const half8*)(gBh + (size_t)j * rstep);
        f32x4 a0 = __builtin_nontemporal_load((const f32x4*)(gA));
        f32x4 a1 = __builtin_nontemporal_load((const f32x4*)(gA + 4));
        p0 = __builtin_nontemporal_load((const f32x4*)(gA + 32));
        p1 = __builtin_nontemporal_load((const f32x4*)(gA + 36));
        q0 = __builtin_nontemporal_load((const f32x4*)(gA + 64));
        q1 = __builtin_nontemporal_load((const f32x4*)(gA + 68));
        float fv[8];
        *(f32x4*)&fv[0] = a0;
        *(f32x4*)&fv[4] = a1;
        union { _Float16 h[8]; short8 s; } uh, ul;
#pragma unroll
        for (int e = 0; e < 8; e++) {
            const float f = fv[e];
            const _Float16 h = (_Float16)f;
            const float fh = (float)h;
            uh.h[e] = h;
            ul.h[e] = (_Float16)((f - fh) * 4096.0f);
        }
        *(short8*)&Ah[0][aoff] = uh.s;
        *(short8*)&Al[0][aoff] = ul.s;
    }

    for (int k2 = 0; k2 < E1KS; k2 += 64) {
        enc1_step<0>(k2,      gA, gBh, gBl, Ah, Al, bhA, bhB, blS,
                     p0, p1, q0, q1, acc1, acc2, aoff, fr0);
        enc1_step<1>(k2 + 32, gA, gBh, gBl, Ah, Al, bhB, bhA, blS,
                     p0, p1, q0, q1, acc1, acc2, aoff, fr0);
    }

    // swapped fragment: row = bm+i*16+lm ; cols = w*64+j*16+lq*4+{0..3}
    float* P = part + (size_t)blockIdx.z * BB * 256;
    const float inv = 0.000244140625f;   // 2^-12
#pragma unroll
    for (int i = 0; i < 4; i++) {
        const int row = bm + i * 16 + lm;
#pragma unroll
        for (int j = 0; j < 4; j++) {
            const int colb = w * 64 + j * 16 + lq * 4;
            float o[4];
#pragma unroll
            for (int r = 0; r < 4; r++)
                o[r] = acc1[i][j][r] + inv * acc2[i][j][r];
            *(f32x4*)&P[(size_t)row * 256 + colb] = *(f32x4*)o;
        }
    }
}

// ---------------- enc2: combine1 fused into the A-path ----------------------
// h2 = leaky( leaky(sum4(part)+be1) @ We2 + be2 ). A value = combine_act's
// exact order: (((p0+p1)+p2)+p3)+be1 -> leaky -> Dekker split. h1 never
// materialized. bias be1 staged in LDS (reads never touch vmcnt FIFO).
struct AQuad { f32x4 a0, b0, c0, d0, a1, b1, c1, d1; };

__device__ __forceinline__ void enc2_convert(
    const AQuad& P, const float* bias_s, int kabs,
    short (&AhD)[2048], short (&AlD)[2048], int aoff)
{
    f32x4 s0 = ((P.a0 + P.b0) + P.c0) + P.d0;
    f32x4 s1 = ((P.a1 + P.b1) + P.c1) + P.d1;
    float fv[8];
#pragma unroll
    for (int c = 0; c < 4; c++) {
        float v = s0[c] + bias_s[kabs + c];
        fv[c] = (v > 0.f) ? v : 0.01f * v;
    }
#pragma unroll
    for (int c = 0; c < 4; c++) {
        float v = s1[c] + bias_s[kabs + 4 + c];
        fv[4 + c] = (v > 0.f) ? v : 0.01f * v;
    }
    union { _Float16 h[8]; short8 s; } uh, ul;
#pragma unroll
    for (int e = 0; e < 8; e++) {
        const float f = fv[e];
        const _Float16 h = (_Float16)f;
        const float fh = (float)h;
        uh.h[e] = h;
        ul.h[e] = (_Float16)((f - fh) * 4096.0f);
    }
    *(short8*)&AhD[aoff] = uh.s;
    *(short8*)&AlD[aoff] = ul.s;
}

__device__ __forceinline__ void enc2_ldraw(AQuad& P, const float* g, size_t PS) {
    P.a0 = *(const f32x4*)(g);
    P.b0 = *(const f32x4*)(g + PS);
    P.c0 = *(const f32x4*)(g + 2 * PS);
    P.d0 = *(const f32x4*)(g + 3 * PS);
    P.a1 = *(const f32x4*)(g + 4);
    P.b1 = *(const f32x4*)(g + PS + 4);
    P.c1 = *(const f32x4*)(g + 2 * PS + 4);
    P.d1 = *(const f32x4*)(g + 3 * PS + 4);
}

template<int BUF>
__device__ __forceinline__ void enc2_step(
    int K0,
    const float* __restrict__ gA, size_t PS,
    const unsigned short* __restrict__ gBh,
    const unsigned short* __restrict__ gBl,
    short (&Ah)[2][2048], short (&Al)[2][2048],
    half8 (&bhC)[2], half8 (&bhN)[2], half8 (&blS)[2],
    AQuad& P, const float* bias_s, int kb,
    f32x4 (&acc1)[4][2], f32x4 (&acc2)[4][2],
    int aoff, int fr0)
{
    constexpr size_t rstep = (size_t)16 * 256;
    const int kn1 = K0 + 32, kn2 = K0 + 64;
    lds_barrier();
#pragma unroll
    for (int j = 0; j < 2; j++)
        blS[j] = *(const half8*)(gBl + (size_t)j * rstep + K0);
    if (kn1 < 256) {
#pragma unroll
        for (int j = 0; j < 2; j++)
            bhN[j] = *(const half8*)(gBh + (size_t)j * rstep + kn1);
    }
    AQuad F;
    if (kn2 < 256) enc2_ldraw(F, gA + kn2, PS);
    half8 ah[4];
#pragma unroll
    for (int i = 0; i < 4; i++)
        ah[i] = *(const half8*)&Ah[BUF][(i << 9) + fr0];
#pragma unroll
    for (int i = 0; i < 4; i++)
#pragma unroll
        for (int j = 0; j < 2; j++)
            acc1[i][j] = __builtin_amdgcn_mfma_f32_16x16x32_f16(
                ah[i], bhC[j], acc1[i][j], 0, 0, 0);
#pragma unroll
    for (int i = 0; i < 4; i++)
#pragma unroll
        for (int j = 0; j < 2; j++)
            acc2[i][j] = __builtin_amdgcn_mfma_f32_16x16x32_f16(
                ah[i], blS[j], acc2[i][j], 0, 0, 0);
    half8 al[4];
#pragma unroll
    for (int i = 0; i < 4; i++)
        al[i] = *(const half8*)&Al[BUF][(i << 9) + fr0];
#pragma unroll
    for (int i = 0; i < 4; i++)
#pragma unroll
        for (int j = 0; j < 2; j++)
            acc2[i][j] = __builtin_amdgcn_mfma_f32_16x16x32_f16(
                al[i], bhC[j], acc2[i][j], 0, 0, 0);
    if (kn1 < 256)
        enc2_convert(P, bias_s, kb + kn1, Ah[BUF ^ 1], Al[BUF ^ 1], aoff);
    if (kn2 < 256) P = F;
}

__global__ __launch_bounds__(256, 2) void gemm_f16x2_enc2(
    const float* __restrict__ part,          // [4][16384][256] f32 partials
    const unsigned short* __restrict__ Bh,   // 128 x 256 f16 (We2^T hi)
    const unsigned short* __restrict__ Bl,   // 128 x 256 f16 (We2^T lo*2^12)
    const float* __restrict__ be1,           // 256 (A bias)
    const float* __restrict__ be2,           // 128 (out bias)
    float* __restrict__ Cf)                  // 16384 x 128
{
    constexpr size_t PS = (size_t)BB * 256;
    __shared__ short Ah[2][2048];
    __shared__ short Al[2][2048];
    __shared__ float bias_s[256];
    const int tid = threadIdx.x;
    const int l = tid & 63, w = tid >> 6;
    const int lm = l & 15, lq = l >> 4;
    const int bm = blockIdx.y * 64;

    const float* gA = part + (size_t)(bm + w * 16 + lm) * 256 + lq * 8;
    const unsigned short* gBh = Bh + (size_t)(w * 32 + lm) * 256 + lq * 8;
    const unsigned short* gBl = Bl + (size_t)(w * 32 + lm) * 256 + lq * 8;
    constexpr size_t rstep = (size_t)16 * 256;

    const int aoff = (w << 9) + (l << 3);
    const int fr0 = (lq << 7) + (lm << 3);
    const int kb = lq * 8;                  // thread's k offset within chunk

    bias_s[tid] = be1[tid];
    __syncthreads();

    f32x4 acc1[4][2], acc2[4][2];
#pragma unroll
    for (int i = 0; i < 4; i++)
#pragma unroll
        for (int j = 0; j < 2; j++) {
            acc1[i][j] = (f32x4){0.f, 0.f, 0.f, 0.f};
            acc2[i][j] = (f32x4){0.f, 0.f, 0.f, 0.f};
        }

    half8 bhA[2], bhB[2], blS[2];
    AQuad P;

    // prologue: B(0) hi; A(0) fused-convert -> LDS[0]; A(32) raw -> P
    {
#pragma unroll
        for (int j = 0; j < 2; j++)
            bhA[j] = *(const half8*)(gBh + (size_t)j * rstep);
        AQuad A0;
        enc2_ldraw(A0, gA, PS);
        enc2_ldraw(P, gA + 32, PS);
        enc2_convert(A0, bias_s, kb, Ah[0], Al[0], aoff);
    }

    for (int k2 = 0; k2 < 256; k2 += 64) {
        enc2_step<0>(k2,      gA, PS, gBh, gBl, Ah, Al, bhA, bhB, blS,
                     P, bias_s, kb, acc1, acc2, aoff, fr0);
        enc2_step<1>(k2 + 32, gA, PS, gBh, gBl, Ah, Al, bhB, bhA, blS,
                     P, bias_s, kb, acc1, acc2, aoff, fr0);
    }

    const float inv = 0.000244140625f;   // 2^-12
#pragma unroll
    for (int i = 0; i < 4; i++)
#pragma unroll
        for (int j = 0; j < 2; j++) {
            const int col = w * 32 + j * 16 + lm;
            const float bv = be2[col];
#pragma unroll
            for (int r = 0; r < 4; r++) {
                const int row = bm + i * 16 + lq * 4 + r;
                float v = acc1[i][j][r] + inv * acc2[i][j][r] + bv;
                v = (v > 0.f) ? v : 0.01f * v;
                Cf[(size_t)row * 128 + col] = v;
            }
        }
}

// ---------------- mid GEMMs: fp16x2 MFMA, fused bias+leaky ------------------
template<int BUF, int NJ, int KLEN>
__device__ __forceinline__ void mid_step(
    int K0,
    const float* __restrict__ gA,
    const unsigned short* __restrict__ gBh,
    const unsigned short* __restrict__ gBl,
    short (&Ah)[2][2048], short (&Al)[2][2048],
    half8 (&bhC)[NJ], half8 (&bhN)[NJ], half8 (&blS)[NJ],
    f32x4& p0, f32x4& p1,
    f32x4 (&acc1)[4][NJ], f32x4 (&acc2)[4][NJ],
    int aoff, int fr0)
{
    constexpr size_t rstep = (size_t)16 * KLEN;
    const int kn1 = K0 + 32, kn2 = K0 + 64;
    lds_barrier();
#pragma unroll
    for (int j = 0; j < NJ; j++)
        blS[j] = *(const half8*)(gBl + (size_t)j * rstep + K0);
    if (kn1 < KLEN) {
#pragma unroll
        for (int j = 0; j < NJ; j++)
            bhN[j] = *(const half8*)(gBh + (size_t)j * rstep + kn1);
    }
    f32x4 f0, f1;
    if (kn2 < KLEN) {
        f0 = *(const f32x4*)(gA + kn2);
        f1 = *(const f32x4*)(gA + kn2 + 4);
    }
    half8 ah[4];
#pragma unroll
    for (int i = 0; i < 4; i++)
        ah[i] = *(const half8*)&Ah[BUF][(i << 9) + fr0];
#pragma unroll
    for (int i = 0; i < 4; i++)
#pragma unroll
        for (int j = 0; j < NJ; j++)
            acc1[i][j] = __builtin_amdgcn_mfma_f32_16x16x32_f16(
                ah[i], bhC[j], acc1[i][j], 0, 0, 0);
#pragma unroll
    for (int i = 0; i < 4; i++)
#pragma unroll
        for (int j = 0; j < NJ; j++)
            acc2[i][j] = __builtin_amdgcn_mfma_f32_16x16x32_f16(
                ah[i], blS[j], acc2[i][j], 0, 0, 0);
    half8 al[4];
#pragma unroll
    for (int i = 0; i < 4; i++)
        al[i] = *(const half8*)&Al[BUF][(i << 9) + fr0];
#pragma unroll
    for (int i = 0; i < 4; i++)
#pragma unroll
        for (int j = 0; j < NJ; j++)
            acc2[i][j] = __builtin_amdgcn_mfma_f32_16x16x32_f16(
                al[i], bhC[j], acc2[i][j], 0, 0, 0);
    if (kn1 < KLEN) {
        float fv[8];
        *(f32x4*)&fv[0] = p0;
        *(f32x4*)&fv[4] = p1;
        union { _Float16 h[8]; short8 s; } uh, ul;
#pragma unroll
        for (int e = 0; e < 8; e++) {
            const float f = fv[e];
            const _Float16 h = (_Float16)f;
            const float fh = (float)h;
            uh.h[e] = h;
            ul.h[e] = (_Float16)((f - fh) * 4096.0f);
        }
        *(short8*)&Ah[BUF ^ 1][aoff] = uh.s;
        *(short8*)&Al[BUF ^ 1][aoff] = ul.s;
    }
    if (kn2 < KLEN) { p0 = f0; p1 = f1; }
}

template<int NJ, int KLEN, int ACT>
__global__ __launch_bounds__(256, 2) void gemm_f16x2_mid(
    const float* __restrict__ A,             // M x KLEN f32 row-major
    const unsigned short* __restrict__ Bh,   // N x KLEN f16 (W^T hi)
    const unsigned short* __restrict__ Bl,   // N x KLEN f16 (W^T lo*2^12)
    const float* __restrict__ bias,
    float* __restrict__ Cf, unsigned short* __restrict__ Cb)
{
    __shared__ short Ah[2][2048];
    __shared__ short Al[2][2048];
    const int tid = threadIdx.x;
    const int l = tid & 63, w = tid >> 6;
    const int lm = l & 15, lq = l >> 4;
    const int bm = blockIdx.y * 64;
    const int bn = blockIdx.x * (64 * NJ);
    const int N = gridDim.x * 64 * NJ;

    const float* gA = A + (size_t)(bm + w * 16 + lm) * KLEN + lq * 8;
    const unsigned short* gBh = Bh + (size_t)(bn + w * (16 * NJ) + lm) * KLEN + lq * 8;
    const unsigned short* gBl = Bl + (size_t)(bn + w * (16 * NJ) + lm) * KLEN + lq * 8;
    constexpr size_t rstep = (size_t)16 * KLEN;

    const int aoff = (w << 9) + (l << 3);
    const int fr0 = (lq << 7) + (lm << 3);

    f32x4 acc1[4][NJ], acc2[4][NJ];
#pragma unroll
    for (int i = 0; i < 4; i++)
#pragma unroll
        for (int j = 0; j < NJ; j++) {
            acc1[i][j] = (f32x4){0.f, 0.f, 0.f, 0.f};
            acc2[i][j] = (f32x4){0.f, 0.f, 0.f, 0.f};
        }

    half8 bhA[NJ], bhB[NJ], blS[NJ];
    f32x4 p0, p1;

    {
#pragma unroll
        for (int j = 0; j < NJ; j++)
            bhA[j] = *(const half8*)(gBh + (size_t)j * rstep);
        f32x4 a0 = *(const f32x4*)(gA);
        f32x4 a1 = *(const f32x4*)(gA + 4);
        p0 = *(const f32x4*)(gA + 32);
        p1 = *(const f32x4*)(gA + 36);
        float fv[8];
        *(f32x4*)&fv[0] = a0;
        *(f32x4*)&fv[4] = a1;
        union { _Float16 h[8]; short8 s; } uh, ul;
#pragma unroll
        for (int e = 0; e < 8; e++) {
            const float f = fv[e];
            const _Float16 h = (_Float16)f;
            const float fh = (float)h;
            uh.h[e] = h;
            ul.h[e] = (_Float16)((f - fh) * 4096.0f);
        }
        *(short8*)&Ah[0][aoff] = uh.s;
        *(short8*)&Al[0][aoff] = ul.s;
    }

    for (int k2 = 0; k2 < KLEN; k2 += 64) {
        mid_step<0, NJ, KLEN>(k2,      gA, gBh, gBl, Ah, Al, bhA, bhB, blS,
                              p0, p1, acc1, acc2, aoff, fr0);
        mid_step<1, NJ, KLEN>(k2 + 32, gA, gBh, gBl, Ah, Al, bhB, bhA, blS,
                              p0, p1, acc1, acc2, aoff, fr0);
    }

    const float inv = 0.000244140625f;   // 2^-12
#pragma unroll
    for (int i = 0; i < 4; i++)
#pragma unroll
        for (int j = 0; j < NJ; j++) {
            const int col = bn + w * (16 * NJ) + j * 16 + lm;
            const float bv = bias[col];
#pragma unroll
            for (int r = 0; r < 4; r++) {
                const int row = bm + i * 16 + lq * 4 + r;
                float v = acc1[i][j][r] + inv * acc2[i][j][r] + bv;
                v = (v > 0.f) ? v : 0.01f * v;
                if (ACT == 0) Cf[(size_t)row * N + col] = v;
                else          Cb[(size_t)row * N + col] = f2bf(v);
            }
        }
}

// ---------------- dec3: bf16 MFMA, barrier-free, reg double-buffer ----------
// SWAPPED MFMA operands: fragment holds 4 consecutive cols per reg ->
// float4 stores of the 268 MB X output (4x fewer store instructions).
__device__ __forceinline__ void dec3_step(
    int kn,
    const unsigned short* __restrict__ gA,
    const unsigned short* __restrict__ gB,
    short8 (&afC)[4], short8 (&bfC)[4],
    short8 (&afN)[4], short8 (&bfN)[4],
    f32x4 (&acc)[4][4])
{
    if (kn < 256) {
#pragma unroll
        for (int i = 0; i < 4; i++)
            afN[i] = *(const short8*)(gA + (size_t)i * 16 * 256 + kn);
#pragma unroll
        for (int j = 0; j < 4; j++)
            bfN[j] = *(const short8*)(gB + (size_t)j * 16 * 256 + kn);
    }
#pragma unroll
    for (int i = 0; i < 4; i++)
#pragma unroll
        for (int j = 0; j < 4; j++)
            acc[i][j] = __builtin_amdgcn_mfma_f32_16x16x32_bf16(
                bfC[j], afC[i], acc[i][j], 0, 0, 0);
}

__global__ __launch_bounds__(256) void gemm_bf16_dec3(
    const unsigned short* __restrict__ Ag,   // 16384 x 256 bf16 row-major
    const unsigned short* __restrict__ Bt,   // 4096 x 256 bf16 row-major (Wd3^T)
    const float* __restrict__ bias, float* __restrict__ C)
{
    const int tid = threadIdx.x;
    const int l = tid & 63, w = tid >> 6;
    const int lm = l & 15, lq = l >> 4;
    const int bm = blockIdx.y * 128, bn = blockIdx.x * 128;
    const int wm = (w >> 1) * 64, wn = (w & 1) * 64;

    const unsigned short* gA = Ag + (size_t)(bm + wm + lm) * 256 + lq * 8;
    const unsigned short* gB = Bt + (size_t)(bn + wn + lm) * 256 + lq * 8;

    f32x4 acc[4][4];
#pragma unroll
    for (int i = 0; i < 4; i++)
#pragma unroll
        for (int j = 0; j < 4; j++) acc[i][j] = (f32x4){0.f, 0.f, 0.f, 0.f};

    short8 afA[4], afB[4], bfA[4], bfB[4];
#pragma unroll
    for (int i = 0; i < 4; i++)
        afA[i] = *(const short8*)(gA + (size_t)i * 16 * 256);
#pragma unroll
    for (int j = 0; j < 4; j++)
        bfA[j] = *(const short8*)(gB + (size_t)j * 16 * 256);

    for (int k0 = 0; k0 < 256; k0 += 64) {
        dec3_step(k0 + 32, gA, gB, afA, bfA, afB, bfB, acc);
        dec3_step(k0 + 64, gA, gB, afB, bfB, afA, bfA, acc);
    }

    // swapped fragment: row = bm+wm+i*16+lm ; cols = bn+wn+j*16+lq*4+{0..3}
#pragma unroll
    for (int i = 0; i < 4; i++) {
        const int row = bm + wm + i * 16 + lm;
#pragma unroll
        for (int j = 0; j < 4; j++) {
            const int colb = bn + wn + j * 16 + lq * 4;
            const f32x4 bv = *(const f32x4*)(bias + colb);
            float o[4];
#pragma unroll
            for (int r = 0; r < 4; r++) {
                float v = acc[i][j][r] + bv[r];
                o[r] = 1.0f / (1.0f + __expf(-v));
            }
            *(f32x4*)(C + (size_t)row * 4096 + colb) = *(f32x4*)o;
        }
    }
}

// ---------------- vq: MFMA scores + argmin + gather, 2-chunk cols -----------
template<int CH>
__device__ __forceinline__ void vq_chunk(
    int w, int lm, int lq, int fr0,
    const short* Ahh, const short* All,
    const unsigned short* __restrict__ cbTh,
    const unsigned short* __restrict__ cbTl,
    const float* __restrict__ w2g,
    float (&bdv)[2][4], int (&bkv)[2][4])
{
    const unsigned short* gBh = cbTh + (size_t)(w * 128 + CH * 64 + lm) * 64 + lq * 8;
    const unsigned short* gBl = cbTl + (size_t)(w * 128 + CH * 64 + lm) * 64 + lq * 8;
    half8 bh0[4], bl0[4], bh1[4], bl1[4];
#pragma unroll
    for (int j = 0; j < 4; j++) {
        bh0[j] = *(const half8*)(gBh + (size_t)j * 1024);
        bl0[j] = *(const half8*)(gBl + (size_t)j * 1024);
        bh1[j] = *(const half8*)(gBh + (size_t)j * 1024 + 32);
        bl1[j] = *(const half8*)(gBl + (size_t)j * 1024 + 32);
    }
    half8 ah0[2], al0[2], ah1[2], al1[2];
#pragma unroll
    for (int i = 0; i < 2; i++) {
        ah0[i] = *(const half8*)&Ahh[i * 1024 + fr0];
        al0[i] = *(const half8*)&All[i * 1024 + fr0];
        ah1[i] = *(const half8*)&Ahh[i * 1024 + 512 + fr0];
        al1[i] = *(const half8*)&All[i * 1024 + 512 + fr0];
    }
    f32x4 acc1[2][4], acc2[2][4];
#pragma unroll
    for (int i = 0; i < 2; i++)
#pragma unroll
        for (int j = 0; j < 4; j++) {
            acc1[i][j] = (f32x4){0.f, 0.f, 0.f, 0.f};
            acc2[i][j] = (f32x4){0.f, 0.f, 0.f, 0.f};
        }
#pragma unroll
    for (int i = 0; i < 2; i++)
#pragma unroll
        for (int j = 0; j < 4; j++)
            acc1[i][j] = __builtin_amdgcn_mfma_f32_16x16x32_f16(
                ah0[i], bh0[j], acc1[i][j], 0, 0, 0);
#pragma unroll
    for (int i = 0; i < 2; i++)
#pragma unroll
        for (int j = 0; j < 4; j++)
            acc2[i][j] = __builtin_amdgcn_mfma_f32_16x16x32_f16(
                al0[i], bh0[j], acc2[i][j], 0, 0, 0);
#pragma unroll
    for (int i = 0; i < 2; i++)
#pragma unroll
        for (int j = 0; j < 4; j++)
            acc2[i][j] = __builtin_amdgcn_mfma_f32_16x16x32_f16(
                ah0[i], bl0[j], acc2[i][j], 0, 0, 0);
#pragma unroll
    for (int i = 0; i < 2; i++)
#pragma unroll
        for (int j = 0; j < 4; j++)
            acc1[i][j] = __builtin_amdgcn_mfma_f32_16x16x32_f16(
                ah1[i], bh1[j], acc1[i][j], 0, 0, 0);
#pragma unroll
    for (int i = 0; i < 2; i++)
#pragma unroll
        for (int j = 0; j < 4; j++)
            acc2[i][j] = __builtin_amdgcn_mfma_f32_16x16x32_f16(
                ah1[i], bl1[j], acc2[i][j], 0, 0, 0);
#pragma unroll
    for (int i = 0; i < 2; i++)
#pragma unroll
        for (int j = 0; j < 4; j++)
            acc2[i][j] = __builtin_amdgcn_mfma_f32_16x16x32_f16(
                al1[i], bh1[j], acc2[i][j], 0, 0, 0);

    const float inv = 0.000244140625f;   // 2^-12
    float w2v[4];
#pragma unroll
    for (int j = 0; j < 4; j++) w2v[j] = w2g[w * 128 + CH * 64 + j * 16 + lm];
#pragma unroll
    for (int i = 0; i < 2; i++)
#pragma unroll
        for (int r = 0; r < 4; r++) {
            float bd = bdv[i][r]; int bk = bkv[i][r];
#pragma unroll
            for (int j = 0; j < 4; j++) {
                const float s = acc1[i][j][r] + inv * acc2[i][j][r];
                const float dsc = w2v[j] - 2.0f * s;
                const int kc = w * 128 + CH * 64 + j * 16 + lm;
                if (dsc < bd || (dsc == bd && kc < bk)) { bd = dsc; bk = kc; }
            }
            bdv[i][r] = bd; bkv[i][r] = bk;
        }
}

__global__ __launch_bounds__(256) void vq_mfma(
    const float* __restrict__ ze, const float* __restrict__ cb,
    const unsigned short* __restrict__ cbTh,   // 512 x 64 f16 (cb^T hi)
    const unsigned short* __restrict__ cbTl,   // 512 x 64 f16 (cb^T lo*2^12)
    const float* __restrict__ w2g,             // 512 f32
    float* __restrict__ idxf, float* __restrict__ zq, float* __restrict__ emb)
{
    __shared__ short Ahh[2048], All[2048];   // 2 t-blocks x [ks][lq][lm][8]
    __shared__ float As[64][33];             // f32 [d][row], conflict-free
    __shared__ float redv[32][4];
    __shared__ int   redk[32][4];
    __shared__ int   kq[32];
    const int tid = threadIdx.x;
    const int l = tid & 63, w = tid >> 6;
    const int lm = l & 15, lq = l >> 4;
    const int b0 = blockIdx.x * 4;           // 4 samples -> 32 rows

    // A-prep: 2048 floats (4 samples) -> As f32 + hi/lo frag-order LDS
#pragma unroll
    for (int ff = 0; ff < 2; ff++) {
        const int e = (tid + ff * 256) * 4;
        const int s = e >> 9, r = e & 511, d = r >> 3, m = r & 7;
        const f32x4 v = *(const f32x4*)(ze + (size_t)b0 * 512 + e);
#pragma unroll
        for (int c = 0; c < 4; c++) {
            const float fv = v[c];
            const int row = s * 8 + m + c;
            As[d][row] = fv;
            const _Float16 h = (_Float16)fv;
            const float fh = (float)h;
            const _Float16 lo = (_Float16)((fv - fh) * 4096.0f);
            union { _Float16 hf; unsigned short u; } ch, cl;
            ch.hf = h; cl.hf = lo;
            const int off = (row >> 4) * 1024 + (d >> 5) * 512 +
                            ((d >> 3) & 3) * 128 + (row & 15) * 8 + (d & 7);
            Ahh[off] = (short)ch.u;
            All[off] = (short)cl.u;
        }
    }
    __syncthreads();

    const int fr0 = lq * 128 + lm * 8;
    float bdv[2][4];
    int   bkv[2][4];
#pragma unroll
    for (int i = 0; i < 2; i++)
#pragma unroll
        for (int r = 0; r < 4; r++) { bdv[i][r] = 3.4e38f; bkv[i][r] = 1 << 30; }

    vq_chunk<0>(w, lm, lq, fr0, Ahh, All, cbTh, cbTl, w2g, bdv, bkv);
    vq_chunk<1>(w, lm, lq, fr0, Ahh, All, cbTh, cbTl, w2g, bdv, bkv);

    // shuffle over lm (16 lanes), then LDS over waves
#pragma unroll
    for (int i = 0; i < 2; i++)
#pragma unroll
        for (int r = 0; r < 4; r++) {
            float bd = bdv[i][r]; int bk = bkv[i][r];
#pragma unroll
            for (int off = 1; off < 16; off <<= 1) {
                const float od = __shfl_xor(bd, off);
                const int   ok = __shfl_xor(bk, off);
                if (od < bd || (od == bd && ok < bk)) { bd = od; bk = ok; }
            }
            if (lm == 0) {
                const int row = i * 16 + lq * 4 + r;
                redv[row][w] = bd;
                redk[row][w] = bk;
            }
        }
    __syncthreads();

    if (tid < 32) {
        float bd = redv[tid][0]; int bk = redk[tid][0];
#pragma unroll
        for (int ww = 1; ww < 4; ww++) {
            const float od = redv[tid][ww];
            const int   ok = redk[tid][ww];
            if (od < bd || (od == bd && ok < bk)) { bd = od; bk = ok; }
        }
        idxf[(size_t)b0 * 8 + tid] = (float)bk;
        kq[tid] = bk;
    }
    __syncthreads();

    // gather: thread t -> (sample s = t>>6, d = t&63), all 8 m
    {
        const int ss = tid >> 6, dd = tid & 63;
        float zq8[8], em8[8];
#pragma unroll
        for (int mm = 0; mm < 8; mm++) {
            const int k = kq[ss * 8 + mm];
            const float q = cb[dd * 512 + k];     // exact f32 codebook
            const float z = As[dd][ss * 8 + mm];
            em8[mm] = q;
            zq8[mm] = z + (q - z);
        }
        float* zqp = zq + (size_t)(b0 + ss) * 512 + dd * 8;
        float* emp = emb + (size_t)(b0 + ss) * 512 + dd * 8;
        *(float4*)zqp = *(float4*)&zq8[0];
        *(float4*)(zqp + 4) = *(float4*)&zq8[4];
        *(float4*)emp = *(float4*)&em8[0];
        *(float4*)(emp + 4) = *(float4*)&em8[4];
    }
}

extern "C" void kernel_launch(void* const* d_in, const int* in_sizes, int n_in,
                              void* d_out, int out_size, void* d_ws, size_t ws_size,
                              hipStream_t stream)
{
    const float* x   = (const float*)d_in[0];
    const float* We1 = (const float*)d_in[1];
    const float* be1 = (const float*)d_in[2];
    const float* We2 = (const float*)d_in[3];
    const float* be2 = (const float*)d_in[4];
    const float* We3 = (const float*)d_in[5];
    const float* be3 = (const float*)d_in[6];
    const float* Wd1 = (const float*)d_in[7];
    const float* bd1 = (const float*)d_in[8];
    const float* Wd2 = (const float*)d_in[9];
    const float* bd2 = (const float*)d_in[10];
    const float* Wd3 = (const float*)d_in[11];
    const float* bd3 = (const float*)d_in[12];
    const float* cb  = (const float*)d_in[13];

    float* out   = (float*)d_out;
    float* o_idx = out;
    float* o_ze  = o_idx + 131072;
    float* o_zq  = o_ze + 8388608;
    float* o_emb = o_zq + 8388608;
    float* o_X   = o_emb + 8388608;   // 268 MB; doubles as split-K scratch

    float* h1 = (float*)d_ws;                          // (unused; kept layout)
    float* h2 = h1 + (size_t)BB * 256;                 // B*128 f32
    // decoder phase reuse:
    float* g1 = h1;                                    // B*128 f32
    unsigned short* g2b = (unsigned short*)(h1 + (size_t)BB * 128); // B*256 bf16
    unsigned short* WT  = (unsigned short*)h2;         // 4096x256 bf16

    // W^T / cb^T fp16 splits in the high region of o_X (dead until dec3;
    // S=4 partials use exactly the first 16,777,216 floats of o_X)
    unsigned short* Bth  = (unsigned short*)(o_X + 16777216);  // We1: 2 MB
    unsigned short* Btl  = Bth + 1048576;                      //      2 MB
    unsigned short* W2h  = Btl + 1048576;   // We2^T 128x256
    unsigned short* W2l  = W2h + 32768;
    unsigned short* W3h  = W2l + 32768;     // We3^T 512x128
    unsigned short* W3l  = W3h + 65536;
    unsigned short* Wd1h = W3l + 65536;     // Wd1^T 128x512
    unsigned short* Wd1l = Wd1h + 65536;
    unsigned short* Wd2h = Wd1l + 65536;    // Wd2^T 256x128
    unsigned short* Wd2l = Wd2h + 32768;
    unsigned short* cbTh = Wd2l + 32768;    // cb^T 512x64
    unsigned short* cbTl = cbTh + 32768;
    float*          w2g  = (float*)(cbTl + 32768);   // 512 f32

    // ALL weight prep in one launch (WT/h2 prep deferred until h2 is dead)
    prep_all<<<dim3(1250), 256, 0, stream>>>(
        We1, Bth, Btl, We2, W2h, W2l, We3, W3h, W3l,
        Wd1, Wd1h, Wd1l, Wd2, Wd2h, Wd2l, cb, cbTh, cbTl, w2g);

    // encoder (enc1 split-K=4: 1024 blocks = 4 blocks/CU)
    gemm_f16x2_enc1<<<dim3(1, 256, 4), 256, 0, stream>>>(x, Bth, Btl, o_X);
    // enc2 with combine1 fused into the A-path (h1 never materialized)
    gemm_f16x2_enc2<<<dim3(1, 256), 256, 0, stream>>>(
        o_X, W2h, W2l, be1, be2, h2);
    gemm_f16x2_mid<4, 128, 0><<<dim3(2, 256), 256, 0, stream>>>(
        h2, W3h, W3l, be3, o_ze, nullptr);

    // Wd3^T cast into h2 (h2 dead after enc3 consumed it)
    transpose_cast<<<dim3(128, 8), 256, 0, stream>>>(Wd3, WT, 256, 4096);

    // VQ: MFMA scores + argmin + gather, fused
    vq_mfma<<<dim3(4096), 256, 0, stream>>>(
        o_ze, cb, cbTh, cbTl, w2g, o_idx, o_zq, o_emb);

    // decoder
    gemm_f16x2_mid<2, 512, 0><<<dim3(1, 256), 256, 0, stream>>>(
        o_zq, Wd1h, Wd1l, bd1, g1, nullptr);
    gemm_f16x2_mid<4, 128, 1><<<dim3(1, 256), 256, 0, stream>>>(
        g1, Wd2h, Wd2l, bd2, nullptr, g2b);
    gemm_bf16_dec3<<<dim3(32, 128), 256, 0, stream>>>(g2b, WT, bd3, o_X);
}

// Round 18
// 947.040 us; speedup vs baseline: 1.0105x; 1.0105x over previous
//
#include <hip/hip_runtime.h>
#include <cstdint>
#include <cstddef>

// ---------------------------------------------------------------------------
// VQ-VAE forward. B=16384 F=4096 H=512 D=64 K=512
// r16 base (best measured 950us) + transpose_cast FOLDED into the vq launch
// (blocks 4096..5119 of vq_mfma do the Wd3->WT cast; no data dependence on
// vq, stream order preserves h2 lifetime). One less serial launch.
// ---------------------------------------------------------------------------

static constexpr int BB = 16384;

typedef __attribute__((ext_vector_type(8))) short short8;
typedef __attribute__((ext_vector_type(8))) _Float16 half8;
typedef __attribute__((ext_vector_type(4))) float f32x4;

__device__ __forceinline__ unsigned short f2bf(float f) {
    union { float f; uint32_t u; } v; v.f = f;
    uint32_t r = (v.u + 0x7FFFu + ((v.u >> 16) & 1u)) >> 16;
    return (unsigned short)r;
}

// producer-fenced raw barrier: my LDS ops done -> barrier. vmcnt NOT drained,
// so global prefetches survive the barrier (unlike __syncthreads).
__device__ __forceinline__ void lds_barrier() {
    asm volatile("s_waitcnt lgkmcnt(0)" ::: "memory");
    __builtin_amdgcn_s_barrier();
    __builtin_amdgcn_sched_barrier(0);
}

// per-block body of the fp16 hi/lo transpose-split (bx,by = tile coords)
__device__ __forceinline__ void tsplit_blk(
    const float* __restrict__ W, unsigned short* __restrict__ Th,
    unsigned short* __restrict__ Tl, int R, int Cc, int bx, int by,
    float (&s)[32][33])
{
    const int tx = threadIdx.x & 31, ty = threadIdx.x >> 5;
    const int c0 = bx * 32, r0 = by * 32;
#pragma unroll
    for (int i = 0; i < 4; i++)
        s[ty + i * 8][tx] = W[(size_t)(r0 + ty + i * 8) * Cc + c0 + tx];
    __syncthreads();
#pragma unroll
    for (int i = 0; i < 4; i++) {
        const float f = s[tx][ty + i * 8];
        const _Float16 h = (_Float16)f;
        const float fh = (float)h;
        const _Float16 lo = (_Float16)((f - fh) * 4096.0f);
        union { _Float16 hf; unsigned short u; } ch, cl;
        ch.hf = h; cl.hf = lo;
        Th[(size_t)(c0 + ty + i * 8) * R + r0 + tx] = ch.u;
        Tl[(size_t)(c0 + ty + i * 8) * R + r0 + tx] = cl.u;
    }
}

// ALL weight prep in one launch. Segments (block ranges):
//   [0,1024)   We1 (8x128)   [1024,1056) We2 (4x8)   [1056,1120) We3 (16x4)
//   [1120,1184) Wd1 (4x16)   [1184,1216) Wd2 (8x4)   [1216,1248) cb  (16x2)
//   [1248,1250) w2g (2 x 256 threads)
__global__ __launch_bounds__(256) void prep_all(
    const float* __restrict__ We1, unsigned short* __restrict__ B1h, unsigned short* __restrict__ B1l,
    const float* __restrict__ We2, unsigned short* __restrict__ W2h, unsigned short* __restrict__ W2l,
    const float* __restrict__ We3, unsigned short* __restrict__ W3h, unsigned short* __restrict__ W3l,
    const float* __restrict__ Wd1, unsigned short* __restrict__ Wd1h, unsigned short* __restrict__ Wd1l,
    const float* __restrict__ Wd2, unsigned short* __restrict__ Wd2h, unsigned short* __restrict__ Wd2l,
    const float* __restrict__ cb,  unsigned short* __restrict__ cbTh, unsigned short* __restrict__ cbTl,
    float* __restrict__ w2g)
{
    __shared__ float s[32][33];
    const int b = blockIdx.x;
    if (b < 1024) {
        tsplit_blk(We1, B1h, B1l, 4096, 256, b & 7, b >> 3, s);
    } else if (b < 1056) {
        const int bb = b - 1024; tsplit_blk(We2, W2h, W2l, 256, 128, bb & 3, bb >> 2, s);
    } else if (b < 1120) {
        const int bb = b - 1056; tsplit_blk(We3, W3h, W3l, 128, 512, bb & 15, bb >> 4, s);
    } else if (b < 1184) {
        const int bb = b - 1120; tsplit_blk(Wd1, Wd1h, Wd1l, 512, 128, bb & 3, bb >> 2, s);
    } else if (b < 1216) {
        const int bb = b - 1184; tsplit_blk(Wd2, Wd2h, Wd2l, 128, 256, bb & 7, bb >> 3, s);
    } else if (b < 1248) {
        const int bb = b - 1216; tsplit_blk(cb, cbTh, cbTl, 64, 512, bb & 15, bb >> 4, s);
    } else {
        const int k = (b - 1248) * 256 + threadIdx.x;
        float sm = 0.f;
        for (int d = 0; d < 64; d++) { float c = cb[d * 512 + k]; sm = fmaf(c, c, sm); }
        w2g[k] = sm;
    }
}

// ---------------- enc1: fp16x2-split MFMA, raw-barrier pipelined ------------
// Split-K=4 (KS=1024 per block). A-queue depth 2: step K0 loads A(K0+96)->f,
// converts p (=A(K0+32)), shifts p<-q<-f.
static constexpr int E1KS = 1024;

template<int BUF>
__device__ __forceinline__ void enc1_step(
    int K0,
    const float* __restrict__ gA,
    const unsigned short* __restrict__ gBh,
    const unsigned short* __restrict__ gBl,
    short (&Ah)[2][2048], short (&Al)[2][2048],
    half8 (&bhC)[4], half8 (&bhN)[4], half8 (&blS)[4],
    f32x4& p0, f32x4& p1, f32x4& q0, f32x4& q1,
    f32x4 (&acc1)[4][4], f32x4 (&acc2)[4][4],
    int aoff, int fr0)
{
    constexpr size_t rstep = (size_t)16 * 4096;   // next t-block (16 rows)
    const int kn1 = K0 + 32, kn3 = K0 + 96;
    lds_barrier();   // LDS[BUF] visible; global prefetches stay in flight
#pragma unroll
    for (int j = 0; j < 4; j++)
        blS[j] = *(const half8*)(gBl + (size_t)j * rstep + K0);
    if (kn1 < E1KS) {
#pragma unroll
        for (int j = 0; j < 4; j++)
            bhN[j] = *(const half8*)(gBh + (size_t)j * rstep + kn1);
    }
    f32x4 f0, f1;
    if (kn3 < E1KS) {
        f0 = __builtin_nontemporal_load((const f32x4*)(gA + kn3));
        f1 = __builtin_nontemporal_load((const f32x4*)(gA + kn3 + 4));
    }
    half8 ah[4];
#pragma unroll
    for (int i = 0; i < 4; i++)
        ah[i] = *(const half8*)&Ah[BUF][(i << 9) + fr0];
#pragma unroll
    for (int i = 0; i < 4; i++)
#pragma unroll
        for (int j = 0; j < 4; j++)
            acc1[i][j] = __builtin_amdgcn_mfma_f32_16x16x32_f16(
                ah[i], bhC[j], acc1[i][j], 0, 0, 0);
#pragma unroll
    for (int i = 0; i < 4; i++)
#pragma unroll
        for (int j = 0; j < 4; j++)
            acc2[i][j] = __builtin_amdgcn_mfma_f32_16x16x32_f16(
                ah[i], blS[j], acc2[i][j], 0, 0, 0);
    half8 al[4];
#pragma unroll
    for (int i = 0; i < 4; i++)
        al[i] = *(const half8*)&Al[BUF][(i << 9) + fr0];
#pragma unroll
    for (int i = 0; i < 4; i++)
#pragma unroll
        for (int j = 0; j < 4; j++)
            acc2[i][j] = __builtin_amdgcn_mfma_f32_16x16x32_f16(
                al[i], bhC[j], acc2[i][j], 0, 0, 0);
    if (kn1 < E1KS) {
        // convert A(K0+32): loaded 2 steps ago -> wait fully hidden
        float fv[8];
        *(f32x4*)&fv[0] = p0;
        *(f32x4*)&fv[4] = p1;
        union { _Float16 h[8]; short8 s; } uh, ul;
#pragma unroll
        for (int e = 0; e < 8; e++) {
            const float f = fv[e];
            const _Float16 h = (_Float16)f;
            const float fh = (float)h;
            uh.h[e] = h;
            ul.h[e] = (_Float16)((f - fh) * 4096.0f);
        }
        *(short8*)&Ah[BUF ^ 1][aoff] = uh.s;
        *(short8*)&Al[BUF ^ 1][aoff] = ul.s;
    }
    p0 = q0; p1 = q1;
    if (kn3 < E1KS) { q0 = f0; q1 = f1; }
}

__global__ __launch_bounds__(256, 2) void gemm_f16x2_enc1(
    const float* __restrict__ X,             // 16384 x 4096 f32
    const unsigned short* __restrict__ Bh,   // 256 x 4096 f16 (We1^T hi)
    const unsigned short* __restrict__ Bl,   // 256 x 4096 f16 (We1^T lo*2^12)
    float* __restrict__ part)                // [4][16384][256] f32
{
    __shared__ short Ah[2][2048];    // 4 t-blocks (64 rows) frag-order, 8 KB
    __shared__ short Al[2][2048];
    const int tid = threadIdx.x;
    const int l = tid & 63, w = tid >> 6;     // 4 waves; wave w -> cols w*64
    const int lm = l & 15, lq = l >> 4;
    const int bm = blockIdx.y * 64;
    const int kStart = blockIdx.z * E1KS;

    const float* gA = X + (size_t)(bm + w * 16 + lm) * 4096 + kStart + lq * 8;
    const unsigned short* gBh = Bh + (size_t)(w * 64 + lm) * 4096 + kStart + lq * 8;
    const unsigned short* gBl = Bl + (size_t)(w * 64 + lm) * 4096 + kStart + lq * 8;
    constexpr size_t rstep = (size_t)16 * 4096;

    const int aoff = (w << 9) + (l << 3);     // A store slot (shorts)
    const int fr0 = (lq << 7) + (lm << 3);    // frag lane offset

    f32x4 acc1[4][4], acc2[4][4];
#pragma unroll
    for (int i = 0; i < 4; i++)
#pragma unroll
        for (int j = 0; j < 4; j++) {
            acc1[i][j] = (f32x4){0.f, 0.f, 0.f, 0.f};
            acc2[i][j] = (f32x4){0.f, 0.f, 0.f, 0.f};
        }

    half8 bhA[4], bhB[4], blS[4];
    f32x4 p0, p1, q0, q1;

    // prologue: B(0) hi -> bhA; A(0) -> convert -> LDS[0];
    // A(32) -> p regs; A(64) -> q regs (queue depth 2)
    {
#pragma unroll
        for (int j = 0; j < 4; j++)
            bhA[j] = *(const half8*)(gBh + (size_t)j * rstep);
        f32x4 a0 = __builtin_nontemporal_load((const f32x4*)(gA));
        f32x4 a1 = __builtin_nontemporal_load((const f32x4*)(gA + 4));
        p0 = __builtin_nontemporal_load((const f32x4*)(gA + 32));
        p1 = __builtin_nontemporal_load((const f32x4*)(gA + 36));
        q0 = __builtin_nontemporal_load((const f32x4*)(gA + 64));
        q1 = __builtin_nontemporal_load((const f32x4*)(gA + 68));
        float fv[8];
        *(f32x4*)&fv[0] = a0;
        *(f32x4*)&fv[4] = a1;
        union { _Float16 h[8]; short8 s; } uh, ul;
#pragma unroll
        for (int e = 0; e < 8; e++) {
            const float f = fv[e];
            const _Float16 h = (_Float16)f;
            const float fh = (float)h;
            uh.h[e] = h;
            ul.h[e] = (_Float16)((f - fh) * 4096.0f);
        }
        *(short8*)&Ah[0][aoff] = uh.s;
        *(short8*)&Al[0][aoff] = ul.s;
    }

    for (int k2 = 0; k2 < E1KS; k2 += 64) {
        enc1_step<0>(k2,      gA, gBh, gBl, Ah, Al, bhA, bhB, blS,
                     p0, p1, q0, q1, acc1, acc2, aoff, fr0);
        enc1_step<1>(k2 + 32, gA, gBh, gBl, Ah, Al, bhB, bhA, blS,
                     p0, p1, q0, q1, acc1, acc2, aoff, fr0);
    }

    float* P = part + (size_t)blockIdx.z * BB * 256;
    const float inv = 0.000244140625f;   // 2^-12
#pragma unroll
    for (int i = 0; i < 4; i++)
#pragma unroll
        for (int j = 0; j < 4; j++) {
            const int col = w * 64 + j * 16 + lm;
#pragma unroll
            for (int r = 0; r < 4; r++) {
                const int row = bm + i * 16 + lq * 4 + r;
                P[(size_t)row * 256 + col] = acc1[i][j][r] + inv * acc2[i][j][r];
            }
        }
}

// ---------------- enc2: combine1 fused into the A-path ----------------------
// h2 = leaky( leaky(sum4(part)+be1) @ We2 + be2 ). A value = combine_act's
// exact order: (((p0+p1)+p2)+p3)+be1 -> leaky -> Dekker split. h1 never
// materialized. bias be1 staged in LDS (reads never touch vmcnt FIFO).
struct AQuad { f32x4 a0, b0, c0, d0, a1, b1, c1, d1; };

__device__ __forceinline__ void enc2_convert(
    const AQuad& P, const float* bias_s, int kabs,
    short (&AhD)[2048], short (&AlD)[2048], int aoff)
{
    f32x4 s0 = ((P.a0 + P.b0) + P.c0) + P.d0;
    f32x4 s1 = ((P.a1 + P.b1) + P.c1) + P.d1;
    float fv[8];
#pragma unroll
    for (int c = 0; c < 4; c++) {
        float v = s0[c] + bias_s[kabs + c];
        fv[c] = (v > 0.f) ? v : 0.01f * v;
    }
#pragma unroll
    for (int c = 0; c < 4; c++) {
        float v = s1[c] + bias_s[kabs + 4 + c];
        fv[4 + c] = (v > 0.f) ? v : 0.01f * v;
    }
    union { _Float16 h[8]; short8 s; } uh, ul;
#pragma unroll
    for (int e = 0; e < 8; e++) {
        const float f = fv[e];
        const _Float16 h = (_Float16)f;
        const float fh = (float)h;
        uh.h[e] = h;
        ul.h[e] = (_Float16)((f - fh) * 4096.0f);
    }
    *(short8*)&AhD[aoff] = uh.s;
    *(short8*)&AlD[aoff] = ul.s;
}

__device__ __forceinline__ void enc2_ldraw(AQuad& P, const float* g, size_t PS) {
    P.a0 = *(const f32x4*)(g);
    P.b0 = *(const f32x4*)(g + PS);
    P.c0 = *(const f32x4*)(g + 2 * PS);
    P.d0 = *(const f32x4*)(g + 3 * PS);
    P.a1 = *(const f32x4*)(g + 4);
    P.b1 = *(const f32x4*)(g + PS + 4);
    P.c1 = *(const f32x4*)(g + 2 * PS + 4);
    P.d1 = *(const f32x4*)(g + 3 * PS + 4);
}

template<int BUF>
__device__ __forceinline__ void enc2_step(
    int K0,
    const float* __restrict__ gA, size_t PS,
    const unsigned short* __restrict__ gBh,
    const unsigned short* __restrict__ gBl,
    short (&Ah)[2][2048], short (&Al)[2][2048],
    half8 (&bhC)[2], half8 (&bhN)[2], half8 (&blS)[2],
    AQuad& P, const float* bias_s, int kb,
    f32x4 (&acc1)[4][2], f32x4 (&acc2)[4][2],
    int aoff, int fr0)
{
    constexpr size_t rstep = (size_t)16 * 256;
    const int kn1 = K0 + 32, kn2 = K0 + 64;
    lds_barrier();
#pragma unroll
    for (int j = 0; j < 2; j++)
        blS[j] = *(const half8*)(gBl + (size_t)j * rstep + K0);
    if (kn1 < 256) {
#pragma unroll
        for (int j = 0; j < 2; j++)
            bhN[j] = *(const half8*)(gBh + (size_t)j * rstep + kn1);
    }
    AQuad F;
    if (kn2 < 256) enc2_ldraw(F, gA + kn2, PS);
    half8 ah[4];
#pragma unroll
    for (int i = 0; i < 4; i++)
        ah[i] = *(const half8*)&Ah[BUF][(i << 9) + fr0];
#pragma unroll
    for (int i = 0; i < 4; i++)
#pragma unroll
        for (int j = 0; j < 2; j++)
            acc1[i][j] = __builtin_amdgcn_mfma_f32_16x16x32_f16(
                ah[i], bhC[j], acc1[i][j], 0, 0, 0);
#pragma unroll
    for (int i = 0; i < 4; i++)
#pragma unroll
        for (int j = 0; j < 2; j++)
            acc2[i][j] = __builtin_amdgcn_mfma_f32_16x16x32_f16(
                ah[i], blS[j], acc2[i][j], 0, 0, 0);
    half8 al[4];
#pragma unroll
    for (int i = 0; i < 4; i++)
        al[i] = *(const half8*)&Al[BUF][(i << 9) + fr0];
#pragma unroll
    for (int i = 0; i < 4; i++)
#pragma unroll
        for (int j = 0; j < 2; j++)
            acc2[i][j] = __builtin_amdgcn_mfma_f32_16x16x32_f16(
                al[i], bhC[j], acc2[i][j], 0, 0, 0);
    if (kn1 < 256)
        enc2_convert(P, bias_s, kb + kn1, Ah[BUF ^ 1], Al[BUF ^ 1], aoff);
    if (kn2 < 256) P = F;
}

__global__ __launch_bounds__(256, 2) void gemm_f16x2_enc2(
    const float* __restrict__ part,          // [4][16384][256] f32 partials
    const unsigned short* __restrict__ Bh,   // 128 x 256 f16 (We2^T hi)
    const unsigned short* __restrict__ Bl,   // 128 x 256 f16 (We2^T lo*2^12)
    const float* __restrict__ be1,           // 256 (A bias)
    const float* __restrict__ be2,           // 128 (out bias)
    float* __restrict__ Cf)                  // 16384 x 128
{
    constexpr size_t PS = (size_t)BB * 256;
    __shared__ short Ah[2][2048];
    __shared__ short Al[2][2048];
    __shared__ float bias_s[256];
    const int tid = threadIdx.x;
    const int l = tid & 63, w = tid >> 6;
    const int lm = l & 15, lq = l >> 4;
    const int bm = blockIdx.y * 64;

    const float* gA = part + (size_t)(bm + w * 16 + lm) * 256 + lq * 8;
    const unsigned short* gBh = Bh + (size_t)(w * 32 + lm) * 256 + lq * 8;
    const unsigned short* gBl = Bl + (size_t)(w * 32 + lm) * 256 + lq * 8;
    constexpr size_t rstep = (size_t)16 * 256;

    const int aoff = (w << 9) + (l << 3);
    const int fr0 = (lq << 7) + (lm << 3);
    const int kb = lq * 8;                  // thread's k offset within chunk

    bias_s[tid] = be1[tid];
    __syncthreads();

    f32x4 acc1[4][2], acc2[4][2];
#pragma unroll
    for (int i = 0; i < 4; i++)
#pragma unroll
        for (int j = 0; j < 2; j++) {
            acc1[i][j] = (f32x4){0.f, 0.f, 0.f, 0.f};
            acc2[i][j] = (f32x4){0.f, 0.f, 0.f, 0.f};
        }

    half8 bhA[2], bhB[2], blS[2];
    AQuad P;

    // prologue: B(0) hi; A(0) fused-convert -> LDS[0]; A(32) raw -> P
    {
#pragma unroll
        for (int j = 0; j < 2; j++)
            bhA[j] = *(const half8*)(gBh + (size_t)j * rstep);
        AQuad A0;
        enc2_ldraw(A0, gA, PS);
        enc2_ldraw(P, gA + 32, PS);
        enc2_convert(A0, bias_s, kb, Ah[0], Al[0], aoff);
    }

    for (int k2 = 0; k2 < 256; k2 += 64) {
        enc2_step<0>(k2,      gA, PS, gBh, gBl, Ah, Al, bhA, bhB, blS,
                     P, bias_s, kb, acc1, acc2, aoff, fr0);
        enc2_step<1>(k2 + 32, gA, PS, gBh, gBl, Ah, Al, bhB, bhA, blS,
                     P, bias_s, kb, acc1, acc2, aoff, fr0);
    }

    const float inv = 0.000244140625f;   // 2^-12
#pragma unroll
    for (int i = 0; i < 4; i++)
#pragma unroll
        for (int j = 0; j < 2; j++) {
            const int col = w * 32 + j * 16 + lm;
            const float bv = be2[col];
#pragma unroll
            for (int r = 0; r < 4; r++) {
                const int row = bm + i * 16 + lq * 4 + r;
                float v = acc1[i][j][r] + inv * acc2[i][j][r] + bv;
                v = (v > 0.f) ? v : 0.01f * v;
                Cf[(size_t)row * 128 + col] = v;
            }
        }
}

// ---------------- mid GEMMs: fp16x2 MFMA, fused bias+leaky ------------------
template<int BUF, int NJ, int KLEN>
__device__ __forceinline__ void mid_step(
    int K0,
    const float* __restrict__ gA,
    const unsigned short* __restrict__ gBh,
    const unsigned short* __restrict__ gBl,
    short (&Ah)[2][2048], short (&Al)[2][2048],
    half8 (&bhC)[NJ], half8 (&bhN)[NJ], half8 (&blS)[NJ],
    f32x4& p0, f32x4& p1,
    f32x4 (&acc1)[4][NJ], f32x4 (&acc2)[4][NJ],
    int aoff, int fr0)
{
    constexpr size_t rstep = (size_t)16 * KLEN;
    const int kn1 = K0 + 32, kn2 = K0 + 64;
    lds_barrier();
#pragma unroll
    for (int j = 0; j < NJ; j++)
        blS[j] = *(const half8*)(gBl + (size_t)j * rstep + K0);
    if (kn1 < KLEN) {
#pragma unroll
        for (int j = 0; j < NJ; j++)
            bhN[j] = *(const half8*)(gBh + (size_t)j * rstep + kn1);
    }
    f32x4 f0, f1;
    if (kn2 < KLEN) {
        f0 = *(const f32x4*)(gA + kn2);
        f1 = *(const f32x4*)(gA + kn2 + 4);
    }
    half8 ah[4];
#pragma unroll
    for (int i = 0; i < 4; i++)
        ah[i] = *(const half8*)&Ah[BUF][(i << 9) + fr0];
#pragma unroll
    for (int i = 0; i < 4; i++)
#pragma unroll
        for (int j = 0; j < NJ; j++)
            acc1[i][j] = __builtin_amdgcn_mfma_f32_16x16x32_f16(
                ah[i], bhC[j], acc1[i][j], 0, 0, 0);
#pragma unroll
    for (int i = 0; i < 4; i++)
#pragma unroll
        for (int j = 0; j < NJ; j++)
            acc2[i][j] = __builtin_amdgcn_mfma_f32_16x16x32_f16(
                ah[i], blS[j], acc2[i][j], 0, 0, 0);
    half8 al[4];
#pragma unroll
    for (int i = 0; i < 4; i++)
        al[i] = *(const half8*)&Al[BUF][(i << 9) + fr0];
#pragma unroll
    for (int i = 0; i < 4; i++)
#pragma unroll
        for (int j = 0; j < NJ; j++)
            acc2[i][j] = __builtin_amdgcn_mfma_f32_16x16x32_f16(
                al[i], bhC[j], acc2[i][j], 0, 0, 0);
    if (kn1 < KLEN) {
        float fv[8];
        *(f32x4*)&fv[0] = p0;
        *(f32x4*)&fv[4] = p1;
        union { _Float16 h[8]; short8 s; } uh, ul;
#pragma unroll
        for (int e = 0; e < 8; e++) {
            const float f = fv[e];
            const _Float16 h = (_Float16)f;
            const float fh = (float)h;
            uh.h[e] = h;
            ul.h[e] = (_Float16)((f - fh) * 4096.0f);
        }
        *(short8*)&Ah[BUF ^ 1][aoff] = uh.s;
        *(short8*)&Al[BUF ^ 1][aoff] = ul.s;
    }
    if (kn2 < KLEN) { p0 = f0; p1 = f1; }
}

template<int NJ, int KLEN, int ACT>
__global__ __launch_bounds__(256, 2) void gemm_f16x2_mid(
    const float* __restrict__ A,             // M x KLEN f32 row-major
    const unsigned short* __restrict__ Bh,   // N x KLEN f16 (W^T hi)
    const unsigned short* __restrict__ Bl,   // N x KLEN f16 (W^T lo*2^12)
    const float* __restrict__ bias,
    float* __restrict__ Cf, unsigned short* __restrict__ Cb)
{
    __shared__ short Ah[2][2048];
    __shared__ short Al[2][2048];
    const int tid = threadIdx.x;
    const int l = tid & 63, w = tid >> 6;
    const int lm = l & 15, lq = l >> 4;
    const int bm = blockIdx.y * 64;
    const int bn = blockIdx.x * (64 * NJ);
    const int N = gridDim.x * 64 * NJ;

    const float* gA = A + (size_t)(bm + w * 16 + lm) * KLEN + lq * 8;
    const unsigned short* gBh = Bh + (size_t)(bn + w * (16 * NJ) + lm) * KLEN + lq * 8;
    const unsigned short* gBl = Bl + (size_t)(bn + w * (16 * NJ) + lm) * KLEN + lq * 8;
    constexpr size_t rstep = (size_t)16 * KLEN;

    const int aoff = (w << 9) + (l << 3);
    const int fr0 = (lq << 7) + (lm << 3);

    f32x4 acc1[4][NJ], acc2[4][NJ];
#pragma unroll
    for (int i = 0; i < 4; i++)
#pragma unroll
        for (int j = 0; j < NJ; j++) {
            acc1[i][j] = (f32x4){0.f, 0.f, 0.f, 0.f};
            acc2[i][j] = (f32x4){0.f, 0.f, 0.f, 0.f};
        }

    half8 bhA[NJ], bhB[NJ], blS[NJ];
    f32x4 p0, p1;

    {
#pragma unroll
        for (int j = 0; j < NJ; j++)
            bhA[j] = *(const half8*)(gBh + (size_t)j * rstep);
        f32x4 a0 = *(const f32x4*)(gA);
        f32x4 a1 = *(const f32x4*)(gA + 4);
        p0 = *(const f32x4*)(gA + 32);
        p1 = *(const f32x4*)(gA + 36);
        float fv[8];
        *(f32x4*)&fv[0] = a0;
        *(f32x4*)&fv[4] = a1;
        union { _Float16 h[8]; short8 s; } uh, ul;
#pragma unroll
        for (int e = 0; e < 8; e++) {
            const float f = fv[e];
            const _Float16 h = (_Float16)f;
            const float fh = (float)h;
            uh.h[e] = h;
            ul.h[e] = (_Float16)((f - fh) * 4096.0f);
        }
        *(short8*)&Ah[0][aoff] = uh.s;
        *(short8*)&Al[0][aoff] = ul.s;
    }

    for (int k2 = 0; k2 < KLEN; k2 += 64) {
        mid_step<0, NJ, KLEN>(k2,      gA, gBh, gBl, Ah, Al, bhA, bhB, blS,
                              p0, p1, acc1, acc2, aoff, fr0);
        mid_step<1, NJ, KLEN>(k2 + 32, gA, gBh, gBl, Ah, Al, bhB, bhA, blS,
                              p0, p1, acc1, acc2, aoff, fr0);
    }

    const float inv = 0.000244140625f;   // 2^-12
#pragma unroll
    for (int i = 0; i < 4; i++)
#pragma unroll
        for (int j = 0; j < NJ; j++) {
            const int col = bn + w * (16 * NJ) + j * 16 + lm;
            const float bv = bias[col];
#pragma unroll
            for (int r = 0; r < 4; r++) {
                const int row = bm + i * 16 + lq * 4 + r;
                float v = acc1[i][j][r] + inv * acc2[i][j][r] + bv;
                v = (v > 0.f) ? v : 0.01f * v;
                if (ACT == 0) Cf[(size_t)row * N + col] = v;
                else          Cb[(size_t)row * N + col] = f2bf(v);
            }
        }
}

// ---------------- dec3: bf16 MFMA, barrier-free, reg double-buffer ----------
__device__ __forceinline__ void dec3_step(
    int kn,
    const unsigned short* __restrict__ gA,
    const unsigned short* __restrict__ gB,
    short8 (&afC)[4], short8 (&bfC)[4],
    short8 (&afN)[4], short8 (&bfN)[4],
    f32x4 (&acc)[4][4])
{
    if (kn < 256) {
#pragma unroll
        for (int i = 0; i < 4; i++)
            afN[i] = *(const short8*)(gA + (size_t)i * 16 * 256 + kn);
#pragma unroll
        for (int j = 0; j < 4; j++)
            bfN[j] = *(const short8*)(gB + (size_t)j * 16 * 256 + kn);
    }
#pragma unroll
    for (int i = 0; i < 4; i++)
#pragma unroll
        for (int j = 0; j < 4; j++)
            acc[i][j] = __builtin_amdgcn_mfma_f32_16x16x32_bf16(
                afC[i], bfC[j], acc[i][j], 0, 0, 0);
}

__global__ __launch_bounds__(256) void gemm_bf16_dec3(
    const unsigned short* __restrict__ Ag,   // 16384 x 256 bf16 row-major
    const unsigned short* __restrict__ Bt,   // 4096 x 256 bf16 row-major (Wd3^T)
    const float* __restrict__ bias, float* __restrict__ C)
{
    const int tid = threadIdx.x;
    const int l = tid & 63, w = tid >> 6;
    const int lm = l & 15, lq = l >> 4;
    const int bm = blockIdx.y * 128, bn = blockIdx.x * 128;
    const int wm = (w >> 1) * 64, wn = (w & 1) * 64;

    const unsigned short* gA = Ag + (size_t)(bm + wm + lm) * 256 + lq * 8;
    const unsigned short* gB = Bt + (size_t)(bn + wn + lm) * 256 + lq * 8;

    f32x4 acc[4][4];
#pragma unroll
    for (int i = 0; i < 4; i++)
#pragma unroll
        for (int j = 0; j < 4; j++) acc[i][j] = (f32x4){0.f, 0.f, 0.f, 0.f};

    short8 afA[4], afB[4], bfA[4], bfB[4];
#pragma unroll
    for (int i = 0; i < 4; i++)
        afA[i] = *(const short8*)(gA + (size_t)i * 16 * 256);
#pragma unroll
    for (int j = 0; j < 4; j++)
        bfA[j] = *(const short8*)(gB + (size_t)j * 16 * 256);

    for (int k0 = 0; k0 < 256; k0 += 64) {
        dec3_step(k0 + 32, gA, gB, afA, bfA, afB, bfB, acc);
        dec3_step(k0 + 64, gA, gB, afB, bfB, afA, bfA, acc);
    }

#pragma unroll
    for (int i = 0; i < 4; i++) {
#pragma unroll
        for (int j = 0; j < 4; j++) {
            const int col = bn + wn + j * 16 + lm;
            const float bv = bias[col];
#pragma unroll
            for (int r = 0; r < 4; r++) {
                const int row = bm + wm + i * 16 + lq * 4 + r;
                float v = acc[i][j][r] + bv;
                v = 1.0f / (1.0f + __expf(-v));
                C[(size_t)row * 4096 + col] = v;
            }
        }
    }
}

// ---------------- vq: MFMA scores + argmin + gather, 2-chunk cols -----------
// Blocks [0,4096): vq. Blocks [4096,5120): Wd3->WT bf16 transpose-cast
// (independent work hidden under vq; h2 free: enc3 already consumed it).
template<int CH>
__device__ __forceinline__ void vq_chunk(
    int w, int lm, int lq, int fr0,
    const short* Ahh, const short* All,
    const unsigned short* __restrict__ cbTh,
    const unsigned short* __restrict__ cbTl,
    const float* __restrict__ w2g,
    float (&bdv)[2][4], int (&bkv)[2][4])
{
    const unsigned short* gBh = cbTh + (size_t)(w * 128 + CH * 64 + lm) * 64 + lq * 8;
    const unsigned short* gBl = cbTl + (size_t)(w * 128 + CH * 64 + lm) * 64 + lq * 8;
    half8 bh0[4], bl0[4], bh1[4], bl1[4];
#pragma unroll
    for (int j = 0; j < 4; j++) {
        bh0[j] = *(const half8*)(gBh + (size_t)j * 1024);
        bl0[j] = *(const half8*)(gBl + (size_t)j * 1024);
        bh1[j] = *(const half8*)(gBh + (size_t)j * 1024 + 32);
        bl1[j] = *(const half8*)(gBl + (size_t)j * 1024 + 32);
    }
    half8 ah0[2], al0[2], ah1[2], al1[2];
#pragma unroll
    for (int i = 0; i < 2; i++) {
        ah0[i] = *(const half8*)&Ahh[i * 1024 + fr0];
        al0[i] = *(const half8*)&All[i * 1024 + fr0];
        ah1[i] = *(const half8*)&Ahh[i * 1024 + 512 + fr0];
        al1[i] = *(const half8*)&All[i * 1024 + 512 + fr0];
    }
    f32x4 acc1[2][4], acc2[2][4];
#pragma unroll
    for (int i = 0; i < 2; i++)
#pragma unroll
        for (int j = 0; j < 4; j++) {
            acc1[i][j] = (f32x4){0.f, 0.f, 0.f, 0.f};
            acc2[i][j] = (f32x4){0.f, 0.f, 0.f, 0.f};
        }
#pragma unroll
    for (int i = 0; i < 2; i++)
#pragma unroll
        for (int j = 0; j < 4; j++)
            acc1[i][j] = __builtin_amdgcn_mfma_f32_16x16x32_f16(
                ah0[i], bh0[j], acc1[i][j], 0, 0, 0);
#pragma unroll
    for (int i = 0; i < 2; i++)
#pragma unroll
        for (int j = 0; j < 4; j++)
            acc2[i][j] = __builtin_amdgcn_mfma_f32_16x16x32_f16(
                al0[i], bh0[j], acc2[i][j], 0, 0, 0);
#pragma unroll
    for (int i = 0; i < 2; i++)
#pragma unroll
        for (int j = 0; j < 4; j++)
            acc2[i][j] = __builtin_amdgcn_mfma_f32_16x16x32_f16(
                ah0[i], bl0[j], acc2[i][j], 0, 0, 0);
#pragma unroll
    for (int i = 0; i < 2; i++)
#pragma unroll
        for (int j = 0; j < 4; j++)
            acc1[i][j] = __builtin_amdgcn_mfma_f32_16x16x32_f16(
                ah1[i], bh1[j], acc1[i][j], 0, 0, 0);
#pragma unroll
    for (int i = 0; i < 2; i++)
#pragma unroll
        for (int j = 0; j < 4; j++)
            acc2[i][j] = __builtin_amdgcn_mfma_f32_16x16x32_f16(
                ah1[i], bl1[j], acc2[i][j], 0, 0, 0);
#pragma unroll
    for (int i = 0; i < 2; i++)
#pragma unroll
        for (int j = 0; j < 4; j++)
            acc2[i][j] = __builtin_amdgcn_mfma_f32_16x16x32_f16(
                al1[i], bh1[j], acc2[i][j], 0, 0, 0);

    const float inv = 0.000244140625f;   // 2^-12
    float w2v[4];
#pragma unroll
    for (int j = 0; j < 4; j++) w2v[j] = w2g[w * 128 + CH * 64 + j * 16 + lm];
#pragma unroll
    for (int i = 0; i < 2; i++)
#pragma unroll
        for (int r = 0; r < 4; r++) {
            float bd = bdv[i][r]; int bk = bkv[i][r];
#pragma unroll
            for (int j = 0; j < 4; j++) {
                const float s = acc1[i][j][r] + inv * acc2[i][j][r];
                const float dsc = w2v[j] - 2.0f * s;
                const int kc = w * 128 + CH * 64 + j * 16 + lm;
                if (dsc < bd || (dsc == bd && kc < bk)) { bd = dsc; bk = kc; }
            }
            bdv[i][r] = bd; bkv[i][r] = bk;
        }
}

__global__ __launch_bounds__(256) void vq_mfma(
    const float* __restrict__ ze, const float* __restrict__ cb,
    const unsigned short* __restrict__ cbTh,   // 512 x 64 f16 (cb^T hi)
    const unsigned short* __restrict__ cbTl,   // 512 x 64 f16 (cb^T lo*2^12)
    const float* __restrict__ w2g,             // 512 f32
    float* __restrict__ idxf, float* __restrict__ zq, float* __restrict__ emb,
    const float* __restrict__ Wd3, unsigned short* __restrict__ WT)
{
    __shared__ short Ahh[2048], All[2048];   // 2 t-blocks x [ks][lq][lm][8]
    __shared__ float As[64][33];             // f32 [d][row], conflict-free
    __shared__ float redv[32][4];
    __shared__ int   redk[32][4];
    __shared__ int   kq[32];
    __shared__ float ts[32][33];             // transpose-branch staging
    const int tid = threadIdx.x;

    if (blockIdx.x >= 4096) {
        // ---- Wd3 -> WT bf16 transpose-cast (r16's transpose_cast body) ----
        const int tb = blockIdx.x - 4096;    // 1024 blocks: 128 x 8 tiles
        const int bx = tb & 127, by = tb >> 7;
        const int tx = tid & 31, ty = tid >> 5;
        const int c0 = bx * 32, r0 = by * 32;
#pragma unroll
        for (int i = 0; i < 4; i++)
            ts[ty + i * 8][tx] = Wd3[(size_t)(r0 + ty + i * 8) * 4096 + c0 + tx];
        __syncthreads();
#pragma unroll
        for (int i = 0; i < 4; i++)
            WT[(size_t)(c0 + ty + i * 8) * 256 + r0 + tx] = f2bf(ts[tx][ty + i * 8]);
        return;
    }

    const int l = tid & 63, w = tid >> 6;
    const int lm = l & 15, lq = l >> 4;
    const int b0 = blockIdx.x * 4;           // 4 samples -> 32 rows

    // A-prep: 2048 floats (4 samples) -> As f32 + hi/lo frag-order LDS
#pragma unroll
    for (int ff = 0; ff < 2; ff++) {
        const int e = (tid + ff * 256) * 4;
        const int s = e >> 9, r = e & 511, d = r >> 3, m = r & 7;
        const f32x4 v = *(const f32x4*)(ze + (size_t)b0 * 512 + e);
#pragma unroll
        for (int c = 0; c < 4; c++) {
            const float fv = v[c];
            const int row = s * 8 + m + c;
            As[d][row] = fv;
            const _Float16 h = (_Float16)fv;
            const float fh = (float)h;
            const _Float16 lo = (_Float16)((fv - fh) * 4096.0f);
            union { _Float16 hf; unsigned short u; } ch, cl;
            ch.hf = h; cl.hf = lo;
            const int off = (row >> 4) * 1024 + (d >> 5) * 512 +
                            ((d >> 3) & 3) * 128 + (row & 15) * 8 + (d & 7);
            Ahh[off] = (short)ch.u;
            All[off] = (short)cl.u;
        }
    }
    __syncthreads();

    const int fr0 = lq * 128 + lm * 8;
    float bdv[2][4];
    int   bkv[2][4];
#pragma unroll
    for (int i = 0; i < 2; i++)
#pragma unroll
        for (int r = 0; r < 4; r++) { bdv[i][r] = 3.4e38f; bkv[i][r] = 1 << 30; }

    vq_chunk<0>(w, lm, lq, fr0, Ahh, All, cbTh, cbTl, w2g, bdv, bkv);
    vq_chunk<1>(w, lm, lq, fr0, Ahh, All, cbTh, cbTl, w2g, bdv, bkv);

    // shuffle over lm (16 lanes), then LDS over waves
#pragma unroll
    for (int i = 0; i < 2; i++)
#pragma unroll
        for (int r = 0; r < 4; r++) {
            float bd = bdv[i][r]; int bk = bkv[i][r];
#pragma unroll
            for (int off = 1; off < 16; off <<= 1) {
                const float od = __shfl_xor(bd, off);
                const int   ok = __shfl_xor(bk, off);
                if (od < bd || (od == bd && ok < bk)) { bd = od; bk = ok; }
            }
            if (lm == 0) {
                const int row = i * 16 + lq * 4 + r;
                redv[row][w] = bd;
                redk[row][w] = bk;
            }
        }
    __syncthreads();

    if (tid < 32) {
        float bd = redv[tid][0]; int bk = redk[tid][0];
#pragma unroll
        for (int ww = 1; ww < 4; ww++) {
            const float od = redv[tid][ww];
            const int   ok = redk[tid][ww];
            if (od < bd || (od == bd && ok < bk)) { bd = od; bk = ok; }
        }
        idxf[(size_t)b0 * 8 + tid] = (float)bk;
        kq[tid] = bk;
    }
    __syncthreads();

    // gather: thread t -> (sample s = t>>6, d = t&63), all 8 m
    {
        const int ss = tid >> 6, dd = tid & 63;
        float zq8[8], em8[8];
#pragma unroll
        for (int mm = 0; mm < 8; mm++) {
            const int k = kq[ss * 8 + mm];
            const float q = cb[dd * 512 + k];     // exact f32 codebook
            const float z = As[dd][ss * 8 + mm];
            em8[mm] = q;
            zq8[mm] = z + (q - z);
        }
        float* zqp = zq + (size_t)(b0 + ss) * 512 + dd * 8;
        float* emp = emb + (size_t)(b0 + ss) * 512 + dd * 8;
        *(float4*)zqp = *(float4*)&zq8[0];
        *(float4*)(zqp + 4) = *(float4*)&zq8[4];
        *(float4*)emp = *(float4*)&em8[0];
        *(float4*)(emp + 4) = *(float4*)&em8[4];
    }
}

extern "C" void kernel_launch(void* const* d_in, const int* in_sizes, int n_in,
                              void* d_out, int out_size, void* d_ws, size_t ws_size,
                              hipStream_t stream)
{
    const float* x   = (const float*)d_in[0];
    const float* We1 = (const float*)d_in[1];
    const float* be1 = (const float*)d_in[2];
    const float* We2 = (const float*)d_in[3];
    const float* be2 = (const float*)d_in[4];
    const float* We3 = (const float*)d_in[5];
    const float* be3 = (const float*)d_in[6];
    const float* Wd1 = (const float*)d_in[7];
    const float* bd1 = (const float*)d_in[8];
    const float* Wd2 = (const float*)d_in[9];
    const float* bd2 = (const float*)d_in[10];
    const float* Wd3 = (const float*)d_in[11];
    const float* bd3 = (const float*)d_in[12];
    const float* cb  = (const float*)d_in[13];

    float* out   = (float*)d_out;
    float* o_idx = out;
    float* o_ze  = o_idx + 131072;
    float* o_zq  = o_ze + 8388608;
    float* o_emb = o_zq + 8388608;
    float* o_X   = o_emb + 8388608;   // 268 MB; doubles as split-K scratch

    float* h1 = (float*)d_ws;                          // (unused; kept layout)
    float* h2 = h1 + (size_t)BB * 256;                 // B*128 f32
    // decoder phase reuse:
    float* g1 = h1;                                    // B*128 f32
    unsigned short* g2b = (unsigned short*)(h1 + (size_t)BB * 128); // B*256 bf16
    unsigned short* WT  = (unsigned short*)h2;         // 4096x256 bf16

    // W^T / cb^T fp16 splits in the high region of o_X (dead until dec3;
    // S=4 partials use exactly the first 16,777,216 floats of o_X)
    unsigned short* Bth  = (unsigned short*)(o_X + 16777216);  // We1: 2 MB
    unsigned short* Btl  = Bth + 1048576;                      //      2 MB
    unsigned short* W2h  = Btl + 1048576;   // We2^T 128x256
    unsigned short* W2l  = W2h + 32768;
    unsigned short* W3h  = W2l + 32768;     // We3^T 512x128
    unsigned short* W3l  = W3h + 65536;
    unsigned short* Wd1h = W3l + 65536;     // Wd1^T 128x512
    unsigned short* Wd1l = Wd1h + 65536;
    unsigned short* Wd2h = Wd1l + 65536;    // Wd2^T 256x128
    unsigned short* Wd2l = Wd2h + 32768;
    unsigned short* cbTh = Wd2l + 32768;    // cb^T 512x64
    unsigned short* cbTl = cbTh + 32768;
    float*          w2g  = (float*)(cbTl + 32768);   // 512 f32

    // ALL weight prep in one launch (WT/h2 prep deferred until h2 is dead)
    prep_all<<<dim3(1250), 256, 0, stream>>>(
        We1, Bth, Btl, We2, W2h, W2l, We3, W3h, W3l,
        Wd1, Wd1h, Wd1l, Wd2, Wd2h, Wd2l, cb, cbTh, cbTl, w2g);

    // encoder (enc1 split-K=4: 1024 blocks = 4 blocks/CU)
    gemm_f16x2_enc1<<<dim3(1, 256, 4), 256, 0, stream>>>(x, Bth, Btl, o_X);
    // enc2 with combine1 fused into the A-path (h1 never materialized)
    gemm_f16x2_enc2<<<dim3(1, 256), 256, 0, stream>>>(
        o_X, W2h, W2l, be1, be2, h2);
    gemm_f16x2_mid<4, 128, 0><<<dim3(2, 256), 256, 0, stream>>>(
        h2, W3h, W3l, be3, o_ze, nullptr);

    // VQ (blocks 0..4095) + Wd3->WT cast (blocks 4096..5119; h2 dead,
    // enc3 completed via stream order; dec3 reads WT after this kernel)
    vq_mfma<<<dim3(5120), 256, 0, stream>>>(
        o_ze, cb, cbTh, cbTl, w2g, o_idx, o_zq, o_emb, Wd3, WT);

    // decoder
    gemm_f16x2_mid<2, 512, 0><<<dim3(1, 256), 256, 0, stream>>>(
        o_zq, Wd1h, Wd1l, bd1, g1, nullptr);
    gemm_f16x2_mid<4, 128, 1><<<dim3(1, 256), 256, 0, stream>>>(
        g1, Wd2h, Wd2l, bd2, nullptr, g2b);
    gemm_bf16_dec3<<<dim3(32, 128), 256, 0, stream>>>(g2b, WT, bd3, o_X);
}